// Round 10
// baseline (412.354 us; speedup 1.0000x reference)
//
#include <hip/hip_runtime.h>
#include <math.h>

// LearnableProjector: P[u,v] = a[u]*a[v]*sum_{j in common items} t[j];
// per-row top-5 keep, global max-normalize. Output dense [8192][8192] f32.
//
// R10: one mixed-role kernel, 64-thread (1-wave) blocks, grid 2*U.
//  odd blocks : zero-writer for one row (32 nt f32x4 stores, retire fast ->
//               deep outstanding-store queue, high write BW).
//  even blocks: compute one row in a FULL 32KB LDS row, single pass:
//               rolling load->ds_add scatter (no held pair regs -> no
//               spills), b128 ownership scan + sorted-insert, top-5
//               butterfly, atomicMax global max. No barriers (1 wave).
// k_norm splices the <=5 normalized values per row afterwards.

#define EPSF 1e-8f
constexpr int U     = 8192;   // num_users
constexpr int NI    = 4096;   // num_items
constexpr int DEG   = 48;     // edges per item; edges grouped by item
constexpr int TOPK  = 5;
constexpr int MAXDU = 48;     // deg_u <= 48
constexpr int NTB   = 256;    // block size for prep kernels
constexpr int NCW   = MAXDU * DEG / 64;   // 36 scatter slots per lane

typedef float f32x4 __attribute__((ext_vector_type(4)));

// descending sorted insert of (val,idx) into register 5-list (tv*/ti*)
#define INS(val, idx)                                                         \
  if ((val) > tv4) {                                                          \
    if ((val) > tv2) {                                                        \
      if ((val) > tv1) {                                                      \
        if ((val) > tv0) { tv4=tv3;ti4=ti3; tv3=tv2;ti3=ti2; tv2=tv1;ti2=ti1; tv1=tv0;ti1=ti0; tv0=(val);ti0=(idx); } \
        else             { tv4=tv3;ti4=ti3; tv3=tv2;ti3=ti2; tv2=tv1;ti2=ti1; tv1=(val);ti1=(idx); }                   \
      } else             { tv4=tv3;ti4=ti3; tv3=tv2;ti3=ti2; tv2=(val);ti2=(idx); } \
    } else {                                                                  \
      if ((val) > tv3)   { tv4=tv3;ti4=ti3; tv3=(val);ti3=(idx); }            \
      else               { tv4=(val);ti4=(idx); }                             \
    }                                                                         \
  }

// ---------------------------------------------------------------- k_build
__global__ __launch_bounds__(NTB) void k_build(
    const int* __restrict__ uidx, const int* __restrict__ iidx, int M,
    int* __restrict__ cnt, int* __restrict__ degi, int* __restrict__ items) {
  int e = blockIdx.x * NTB + threadIdx.x;
  if (e >= M) return;
  int u = uidx[e];
  int j = iidx[e];
  atomicAdd(&degi[j], 1);
  int slot = atomicAdd(&cnt[u], 1);
  if (slot < MAXDU) items[u * MAXDU + slot] = j;
}

// -------------------------------------------------------------- k_scalars
__global__ __launch_bounds__(NTB) void k_scalars(
    const int* __restrict__ cnt, const int* __restrict__ degi,
    const float* __restrict__ fraud_u, const float* __restrict__ theta,
    const float* __restrict__ gamma, float* __restrict__ a, float* __restrict__ t) {
  int i = blockIdx.x * NTB + threadIdx.x;
  float g = gamma[0];
  if (i < U) {
    float su = log1pf((float)cnt[i]) * expf(g * fraud_u[i]);
    a[i] = sqrtf(su + EPSF);
  }
  if (i < NI) {
    float w  = log1pf(expf(theta[i])) + EPSF;   // softplus + EPS
    float si = log1pf((float)degi[i]);
    t[i] = (si + EPSF) * w;
  }
}

// ---------------------------------------------------------------- k_edges
// val_e[e] = t[i[e]] * a[u[e]]  (gathers done ONCE here, coalesced writes)
__global__ __launch_bounds__(NTB) void k_edges(
    const int* __restrict__ uidx, const int* __restrict__ iidx, int M,
    const float* __restrict__ a, const float* __restrict__ t,
    float* __restrict__ val_e) {
  int e = blockIdx.x * NTB + threadIdx.x;
  if (e >= M) return;
  val_e[e] = t[iidx[e]] * a[uidx[e]];
}

// ----------------------------------------------------------------- k_main
// 1-wave blocks. Odd block -> stream zeros for row b>>1. Even -> compute it.
__global__ __launch_bounds__(64) void k_main(
    const int* __restrict__ uidx, const int* __restrict__ cnt,
    const int* __restrict__ items, const float* __restrict__ a,
    const float* __restrict__ val_e, float* __restrict__ val5,
    int* __restrict__ idx5, unsigned* __restrict__ gmax,
    float* __restrict__ out) {
  __shared__ float Brow[U];              // 32 KB full row (compute role)
  __shared__ int   shj[MAXDU];           // item list, pre-scaled *DEG

  const int b = blockIdx.x, lane = threadIdx.x;
  const int u = b >> 1;
  f32x4* orow = reinterpret_cast<f32x4*>(out + (size_t)u * U);
  const f32x4 zz4 = {0.f, 0.f, 0.f, 0.f};

  if (b & 1) {
    // ---- zero-writer role: 32 nt stores, retire immediately
#pragma unroll
    for (int q = 0; q < U / 4 / 64; ++q)
      __builtin_nontemporal_store(zz4, &orow[q * 64 + lane]);
    return;
  }

  // ---- compute role -------------------------------------------------
  int c = cnt[u]; if (c > MAXDU) c = MAXDU;
  if (lane < c) shj[lane] = items[u * MAXDU + lane] * DEG;
  f32x4* Bv = reinterpret_cast<f32x4*>(Brow);
#pragma unroll
  for (int q = 0; q < U / 4 / 64; ++q) Bv[q * 64 + lane] = zz4;
  asm volatile("s_waitcnt lgkmcnt(0)" ::: "memory");   // shj + zeros done

  // rolling scatter: load edge -> ds_add, nothing held across phases
  const int total = c * DEG;
#pragma unroll
  for (int r = 0; r < NCW; ++r) {
    int x = lane + 64 * r;
    if (x < total) {
      int k = x / DEG;                   // compile-time 48 -> magic-mul
      int e = shj[k] + (x - k * DEG);
      int v = uidx[e];                   // coalesced within item span
      if (v != u) atomicAdd(&Brow[v], val_e[e]);
    }
  }
  asm volatile("s_waitcnt lgkmcnt(0)" ::: "memory");   // all adds done

  // ownership scan: f32x4 slot read by exactly one lane + sorted insert
  const float au = a[u];
  float tv0=-1.f,tv1=-1.f,tv2=-1.f,tv3=-1.f,tv4=-1.f;
  int   ti0=-1,  ti1=-1,  ti2=-1,  ti3=-1,  ti4=-1;
#pragma unroll
  for (int q = 0; q < U / 4 / 64; ++q) {
    f32x4 s4 = Bv[q * 64 + lane];
    int col0 = (q * 64 + lane) * 4;
    if (s4.x > 0.f) { float vl = au * s4.x; INS(vl, col0)     }
    if (s4.y > 0.f) { float vl = au * s4.y; INS(vl, col0 + 1) }
    if (s4.z > 0.f) { float vl = au * s4.z; INS(vl, col0 + 2) }
    if (s4.w > 0.f) { float vl = au * s4.w; INS(vl, col0 + 3) }
  }

  // wave top-5: 5 rounds of butterfly argmax over sorted-list heads
#pragma unroll
  for (int it = 0; it < TOPK; ++it) {
    float bv = tv0; int bi = ti0;
    for (int s = 32; s; s >>= 1) {
      float ov = __shfl_xor(bv, s);
      int   oi = __shfl_xor(bi, s);
      if (ov > bv || (ov == bv && oi < bi)) { bv = ov; bi = oi; }
    }
    if (bi >= 0 && ti0 == bi) {          // pop winner (cols unique per wave)
      tv0=tv1;ti0=ti1; tv1=tv2;ti1=ti2; tv2=tv3;ti2=ti3; tv3=tv4;ti3=ti4;
      tv4=-1.f;ti4=-1;
    }
    if (lane == 0) {
      float sv = bv > 0.f ? bv : 0.f;
      val5[u * TOPK + it] = sv;
      idx5[u * TOPK + it] = bi;
      if (it == 0) atomicMax(gmax, __float_as_uint(sv));  // bits==float order
    }
  }
}

// ----------------------------------------------------------------- k_norm
// Splice the normalized kept values (<= 40960 scattered 4B stores).
__global__ __launch_bounds__(NTB) void k_norm(
    const float* __restrict__ val5, const int* __restrict__ idx5,
    const unsigned* __restrict__ gmax, float* __restrict__ out) {
  int i = blockIdx.x * NTB + threadIdx.x;
  if (i >= U * TOPK) return;
  int ix = idx5[i];
  float v = val5[i];
  if (ix >= 0 && v > 0.f) {
    float inv = 1.f / (__uint_as_float(*gmax) + EPSF);
    out[(size_t)(i / TOPK) * U + ix] = v * inv;
  }
}

// ------------------------------------------------------------------ host
extern "C" void kernel_launch(void* const* d_in, const int* in_sizes, int n_in,
                              void* d_out, int out_size, void* d_ws, size_t ws_size,
                              hipStream_t stream) {
  const int M = in_sizes[0] / 2;                    // 196608
  const int* uidx = (const int*)d_in[0];            // edge_index_ui row 0
  const int* iidx = uidx + M;                       // edge_index_ui row 1
  const float* fraud_u = (const float*)d_in[1];
  // d_in[2] fraud_i: unused (use_item_gamma=False)
  const float* theta = (const float*)d_in[3];
  const float* gamma = (const float*)d_in[4];

  int* ws = (int*)d_ws;
  int*      cnt   = ws;                             // [U]
  int*      degi  = ws + U;                         // [NI]
  unsigned* gmax  = (unsigned*)(ws + U + NI);       // [1] (+3 pad)
  float*    a     = (float*)(ws + U + NI + 4);      // [U]
  float*    t     = a + U;                          // [NI]
  float*    val5  = t + NI;                         // [U*TOPK]
  int*      idx5  = (int*)(val5 + U * TOPK);        // [U*TOPK]
  int*      items = idx5 + U * TOPK;                // [U*MAXDU]
  float*    val_e = (float*)(items + U * MAXDU);    // [M]
  float* out = (float*)d_out;

  (void)hipMemsetAsync(d_ws, 0, (size_t)(U + NI + 4) * sizeof(int), stream);
  k_build  <<<(M + NTB - 1) / NTB, NTB, 0, stream>>>(uidx, iidx, M, cnt, degi, items);
  k_scalars<<<U / NTB,             NTB, 0, stream>>>(cnt, degi, fraud_u, theta, gamma, a, t);
  k_edges  <<<(M + NTB - 1) / NTB, NTB, 0, stream>>>(uidx, iidx, M, a, t, val_e);
  k_main   <<<2 * U,               64,  0, stream>>>(uidx, cnt, items, a, val_e,
                                                     val5, idx5, gmax, out);
  k_norm   <<<(U * TOPK + NTB - 1) / NTB, NTB, 0, stream>>>(val5, idx5, gmax, out);
}

// Round 11
// 217.799 us; speedup vs baseline: 1.8933x; 1.8933x over previous
//
#include <hip/hip_runtime.h>
#include <math.h>

// LearnableProjector: P[u,v] = a[u]*a[v]*sum_{j in common items} t[j];
// per-row top-5 keep (ties included, like reference P >= kth), global
// max-normalize. Output dense [8192][8192] f32.
//
// R11: branchless value-only selection. One row per 256-thr block:
// zero 32KB LDS row -> cooperative scatter (LDS atomics) -> per-lane
// branchless sorted-5 VALUES (10 vmax/vmin per value, no divergence, no
// idx) -> value butterfly merge -> m5 threshold -> predicated compact of
// survivors (val>=m5). Zeros of `out` are written by hipMemsetAsync's
// tuned fill kernel; k_norm splices the <=8 normalized survivors.

#define EPSF 1e-8f
constexpr int U     = 8192;   // num_users
constexpr int NI    = 4096;   // num_items
constexpr int DEG   = 48;     // edges per item; edges grouped by item
constexpr int MAXDU = 48;     // deg_u <= 48
constexpr int NTB   = 256;    // prep kernels block size
constexpr int NT    = 256;    // k_rows block size
constexpr int KS    = 8;      // survivor slots per row (top-5 + tie slack)

typedef float f32x4 __attribute__((ext_vector_type(4)));

// branchless value-only insert into descending t0..t4 (10 full-rate ops)
#define VINS(xin) { float nx = (xin), mx;                                     \
  mx = fmaxf(t0, nx); nx = fminf(t0, nx); t0 = mx;                            \
  mx = fmaxf(t1, nx); nx = fminf(t1, nx); t1 = mx;                            \
  mx = fmaxf(t2, nx); nx = fminf(t2, nx); t2 = mx;                            \
  mx = fmaxf(t3, nx); nx = fminf(t3, nx); t3 = mx;                            \
  t4 = fmaxf(t4, nx); }

// ---------------------------------------------------------------- k_build
__global__ __launch_bounds__(NTB) void k_build(
    const int* __restrict__ uidx, const int* __restrict__ iidx, int M,
    int* __restrict__ cnt, int* __restrict__ degi, int* __restrict__ items) {
  int e = blockIdx.x * NTB + threadIdx.x;
  if (e >= M) return;
  int u = uidx[e];
  int j = iidx[e];
  atomicAdd(&degi[j], 1);
  int slot = atomicAdd(&cnt[u], 1);
  if (slot < MAXDU) items[u * MAXDU + slot] = j;
}

// -------------------------------------------------------------- k_scalars
__global__ __launch_bounds__(NTB) void k_scalars(
    const int* __restrict__ cnt, const int* __restrict__ degi,
    const float* __restrict__ fraud_u, const float* __restrict__ theta,
    const float* __restrict__ gamma, float* __restrict__ a, float* __restrict__ t) {
  int i = blockIdx.x * NTB + threadIdx.x;
  float g = gamma[0];
  if (i < U) {
    float su = log1pf((float)cnt[i]) * expf(g * fraud_u[i]);
    a[i] = sqrtf(su + EPSF);
  }
  if (i < NI) {
    float w  = log1pf(expf(theta[i])) + EPSF;   // softplus + EPS
    float si = log1pf((float)degi[i]);
    t[i] = (si + EPSF) * w;
  }
}

// ---------------------------------------------------------------- k_edges
// val_e[e] = t[i[e]] * a[u[e]]  (gathers done once, coalesced writes)
__global__ __launch_bounds__(NTB) void k_edges(
    const int* __restrict__ uidx, const int* __restrict__ iidx, int M,
    const float* __restrict__ a, const float* __restrict__ t,
    float* __restrict__ val_e) {
  int e = blockIdx.x * NTB + threadIdx.x;
  if (e >= M) return;
  val_e[e] = t[iidx[e]] * a[uidx[e]];
}

// ---------------------------------------------------------------- k_rows
// One row per block. 3 barriers. Branchless value-only top-5 -> threshold
// -> compact survivors (val,col) with row-local LDS counter.
__global__ __launch_bounds__(NT) void k_rows(
    const int* __restrict__ uidx, const int* __restrict__ cnt,
    const int* __restrict__ items, const float* __restrict__ a,
    const float* __restrict__ val_e, float* __restrict__ val5,
    int* __restrict__ idx5, int* __restrict__ nk, unsigned* __restrict__ gmax) {
  __shared__ float row[U];               // 32 KB
  __shared__ int   shj[MAXDU];           // item list, pre-scaled *DEG
  __shared__ float wt[NT / 64][5];       // per-wave top-5 values
  __shared__ int   scnt;

  const int tid = threadIdx.x, lane = tid & 63, wid = tid >> 6;
  const int u = blockIdx.x;
  f32x4* Bv = reinterpret_cast<f32x4*>(row);

  int c = cnt[u]; if (c > MAXDU) c = MAXDU;
  if (tid < c) shj[tid] = items[u * MAXDU + tid] * DEG;
  if (tid == 0) scnt = 0;
  const f32x4 zz4 = {0.f, 0.f, 0.f, 0.f};
#pragma unroll
  for (int q = 0; q < U / 4 / NT; ++q) Bv[q * NT + tid] = zz4;
  __syncthreads();                       // B1: row zeroed, shj ready

  // ---- cooperative scatter: <= 9 edges per thread, LDS atomics
  const int total = c * DEG;
  for (int x = tid; x < total; x += NT) {
    int k = x / DEG;                     // compile-time 48 -> magic-mul
    int e = shj[k] + (x - k * DEG);
    int v = uidx[e];                     // coalesced within item span
    if (v != u) atomicAdd(&row[v], val_e[e]);
  }
  __syncthreads();                       // B2: all adds done

  // ---- per-lane branchless top-5 values over this wave's 2048-slot quarter
  float t0 = 0.f, t1 = 0.f, t2 = 0.f, t3 = 0.f, t4 = 0.f;
  const int qbase = wid * 512;           // f32x4 units: 512 per wave quarter
#pragma unroll
  for (int q = 0; q < 8; ++q) {
    f32x4 s4 = Bv[qbase + q * 64 + lane];
    VINS(s4.x) VINS(s4.y) VINS(s4.z) VINS(s4.w)
  }
  // ---- value-only butterfly merge of sorted-5 lists across 64 lanes
#pragma unroll
  for (int s = 32; s; s >>= 1) {
    float o0 = __shfl_xor(t0, s), o1 = __shfl_xor(t1, s), o2 = __shfl_xor(t2, s),
          o3 = __shfl_xor(t3, s), o4 = __shfl_xor(t4, s);
    VINS(o0) VINS(o1) VINS(o2) VINS(o3) VINS(o4)
  }
  if (lane == 0) { wt[wid][0]=t0; wt[wid][1]=t1; wt[wid][2]=t2; wt[wid][3]=t3; wt[wid][4]=t4; }
  __syncthreads();                       // B3: wave tops ready

  // ---- all threads redundantly merge the 4 wave lists (broadcast reads)
  t0 = wt[0][0]; t1 = wt[0][1]; t2 = wt[0][2]; t3 = wt[0][3]; t4 = wt[0][4];
#pragma unroll
  for (int w = 1; w < NT / 64; ++w) {
    VINS(wt[w][0]) VINS(wt[w][1]) VINS(wt[w][2]) VINS(wt[w][3]) VINS(wt[w][4])
  }
  const float m5 = t4, m1 = t0;
  const float au = a[u];

  // ---- compact survivors (raw val >= m5, positive); rare branch
#pragma unroll
  for (int q = 0; q < 8; ++q) {
    f32x4 s4 = Bv[qbase + q * 64 + lane];
    int col0 = (qbase + q * 64 + lane) * 4;
#pragma unroll
    for (int z = 0; z < 4; ++z) {
      float v = (z == 0) ? s4.x : (z == 1) ? s4.y : (z == 2) ? s4.z : s4.w;
      if (v >= m5 && v > 0.f) {
        int slot = atomicAdd(&scnt, 1);
        if (slot < KS) {
          val5[u * KS + slot] = au * v;
          idx5[u * KS + slot] = col0 + z;
        }
      }
    }
  }
  __syncthreads();                       // scnt final
  if (tid == 0) {
    nk[u] = scnt < KS ? scnt : KS;
    if (m1 > 0.f) atomicMax(gmax, __float_as_uint(au * m1)); // bits==float order
  }
}

// ----------------------------------------------------------------- k_norm
// Splice the normalized kept values (~U*5 scattered 4B stores).
__global__ __launch_bounds__(NTB) void k_norm(
    const float* __restrict__ val5, const int* __restrict__ idx5,
    const int* __restrict__ nk, const unsigned* __restrict__ gmax,
    float* __restrict__ out) {
  int i = blockIdx.x * NTB + threadIdx.x;
  if (i >= U * KS) return;
  int u = i / KS, s = i - u * KS;
  if (s < nk[u]) {
    float inv = 1.f / (__uint_as_float(*gmax) + EPSF);
    out[(size_t)u * U + idx5[i]] = val5[i] * inv;
  }
}

// ------------------------------------------------------------------ host
extern "C" void kernel_launch(void* const* d_in, const int* in_sizes, int n_in,
                              void* d_out, int out_size, void* d_ws, size_t ws_size,
                              hipStream_t stream) {
  const int M = in_sizes[0] / 2;                    // 196608
  const int* uidx = (const int*)d_in[0];            // edge_index_ui row 0
  const int* iidx = uidx + M;                       // edge_index_ui row 1
  const float* fraud_u = (const float*)d_in[1];
  // d_in[2] fraud_i: unused (use_item_gamma=False)
  const float* theta = (const float*)d_in[3];
  const float* gamma = (const float*)d_in[4];

  int* ws = (int*)d_ws;
  int*      cnt   = ws;                             // [U]
  int*      degi  = ws + U;                         // [NI]
  unsigned* gmax  = (unsigned*)(ws + U + NI);       // [1] (+3 pad)
  float*    a     = (float*)(ws + U + NI + 4);      // [U]
  float*    t     = a + U;                          // [NI]
  float*    val5  = t + NI;                         // [U*KS]
  int*      idx5  = (int*)(val5 + U * KS);          // [U*KS]
  int*      nk    = idx5 + U * KS;                  // [U]
  int*      items = nk + U;                         // [U*MAXDU]
  float*    val_e = (float*)(items + U * MAXDU);    // [M]
  float* out = (float*)d_out;

  // zeros of the output: tuned runtime fill kernel (pure writer, no LDS)
  (void)hipMemsetAsync(out, 0, (size_t)U * U * sizeof(float), stream);
  (void)hipMemsetAsync(d_ws, 0, (size_t)(U + NI + 4) * sizeof(int), stream);
  k_build  <<<(M + NTB - 1) / NTB, NTB, 0, stream>>>(uidx, iidx, M, cnt, degi, items);
  k_scalars<<<U / NTB,             NTB, 0, stream>>>(cnt, degi, fraud_u, theta, gamma, a, t);
  k_edges  <<<(M + NTB - 1) / NTB, NTB, 0, stream>>>(uidx, iidx, M, a, t, val_e);
  k_rows   <<<U,                   NT,  0, stream>>>(uidx, cnt, items, a, val_e,
                                                     val5, idx5, nk, gmax);
  k_norm   <<<(U * KS + NTB - 1) / NTB, NTB, 0, stream>>>(val5, idx5, nk, gmax, out);
}

// Round 12
// 193.372 us; speedup vs baseline: 2.1324x; 1.1263x over previous
//
#include <hip/hip_runtime.h>
#include <math.h>

// LearnableProjector: P[u,v] = a[u]*a[v]*sum_{j in common items} t[j];
// per-row top-5 keep (ties included, like reference P >= kth), global
// max-normalize. Output dense [8192][8192] f32.
//
// R12: R11's branchless compute + fused zero-stream (no hipMemset of out;
// the runtime fill kernel wrote 4x traffic, 1.07GB for 268MB). Each block:
// zero 32KB LDS row -> cooperative scatter (LDS atomics) -> branchless
// per-lane sorted-5 VALUES -> butterfly merge -> m5 threshold -> compact
// survivors -> THEN stream the row's zeros to out (stores last: loads are
// all done, queue drains under the next block's compute). k_norm splices
// the <=8 normalized survivors afterwards.

#define EPSF 1e-8f
constexpr int U     = 8192;   // num_users
constexpr int NI    = 4096;   // num_items
constexpr int DEG   = 48;     // edges per item; edges grouped by item
constexpr int MAXDU = 48;     // deg_u <= 48
constexpr int NTB   = 256;    // prep kernels block size
constexpr int NT    = 256;    // k_rows block size
constexpr int KS    = 8;      // survivor slots per row (top-5 + tie slack)

typedef float f32x4 __attribute__((ext_vector_type(4)));

// branchless value-only insert into descending t0..t4 (10 full-rate ops)
#define VINS(xin) { float nx = (xin), mx;                                     \
  mx = fmaxf(t0, nx); nx = fminf(t0, nx); t0 = mx;                            \
  mx = fmaxf(t1, nx); nx = fminf(t1, nx); t1 = mx;                            \
  mx = fmaxf(t2, nx); nx = fminf(t2, nx); t2 = mx;                            \
  mx = fmaxf(t3, nx); nx = fminf(t3, nx); t3 = mx;                            \
  t4 = fmaxf(t4, nx); }

// ---------------------------------------------------------------- k_build
__global__ __launch_bounds__(NTB) void k_build(
    const int* __restrict__ uidx, const int* __restrict__ iidx, int M,
    int* __restrict__ cnt, int* __restrict__ degi, int* __restrict__ items) {
  int e = blockIdx.x * NTB + threadIdx.x;
  if (e >= M) return;
  int u = uidx[e];
  int j = iidx[e];
  atomicAdd(&degi[j], 1);
  int slot = atomicAdd(&cnt[u], 1);
  if (slot < MAXDU) items[u * MAXDU + slot] = j;
}

// -------------------------------------------------------------- k_scalars
__global__ __launch_bounds__(NTB) void k_scalars(
    const int* __restrict__ cnt, const int* __restrict__ degi,
    const float* __restrict__ fraud_u, const float* __restrict__ theta,
    const float* __restrict__ gamma, float* __restrict__ a, float* __restrict__ t) {
  int i = blockIdx.x * NTB + threadIdx.x;
  float g = gamma[0];
  if (i < U) {
    float su = log1pf((float)cnt[i]) * expf(g * fraud_u[i]);
    a[i] = sqrtf(su + EPSF);
  }
  if (i < NI) {
    float w  = log1pf(expf(theta[i])) + EPSF;   // softplus + EPS
    float si = log1pf((float)degi[i]);
    t[i] = (si + EPSF) * w;
  }
}

// ---------------------------------------------------------------- k_edges
// val_e[e] = t[i[e]] * a[u[e]]  (gathers done once, coalesced writes)
__global__ __launch_bounds__(NTB) void k_edges(
    const int* __restrict__ uidx, const int* __restrict__ iidx, int M,
    const float* __restrict__ a, const float* __restrict__ t,
    float* __restrict__ val_e) {
  int e = blockIdx.x * NTB + threadIdx.x;
  if (e >= M) return;
  val_e[e] = t[iidx[e]] * a[uidx[e]];
}

// ---------------------------------------------------------------- k_rows
// One row per block. Branchless value-only top-5 -> threshold -> compact,
// then stream the row's zeros (stores last; drain under next block).
__global__ __launch_bounds__(NT) void k_rows(
    const int* __restrict__ uidx, const int* __restrict__ cnt,
    const int* __restrict__ items, const float* __restrict__ a,
    const float* __restrict__ val_e, float* __restrict__ val5,
    int* __restrict__ idx5, int* __restrict__ nk, unsigned* __restrict__ gmax,
    float* __restrict__ out) {
  __shared__ float row[U];               // 32 KB
  __shared__ int   shj[MAXDU];           // item list, pre-scaled *DEG
  __shared__ float wt[NT / 64][5];       // per-wave top-5 values
  __shared__ int   scnt;

  const int tid = threadIdx.x, lane = tid & 63, wid = tid >> 6;
  const int u = blockIdx.x;
  f32x4* Bv = reinterpret_cast<f32x4*>(row);
  const f32x4 zz4 = {0.f, 0.f, 0.f, 0.f};

  int c = cnt[u]; if (c > MAXDU) c = MAXDU;
  if (tid < c) shj[tid] = items[u * MAXDU + tid] * DEG;
  if (tid == 0) scnt = 0;
#pragma unroll
  for (int q = 0; q < U / 4 / NT; ++q) Bv[q * NT + tid] = zz4;
  __syncthreads();                       // B1: row zeroed, shj ready

  // ---- cooperative scatter: <= 9 edges per thread, LDS atomics
  const int total = c * DEG;
  for (int x = tid; x < total; x += NT) {
    int k = x / DEG;                     // compile-time 48 -> magic-mul
    int e = shj[k] + (x - k * DEG);
    int v = uidx[e];                     // coalesced within item span
    if (v != u) atomicAdd(&row[v], val_e[e]);
  }
  __syncthreads();                       // B2: all adds done

  // ---- per-lane branchless top-5 values over this wave's 2048-slot quarter
  float t0 = 0.f, t1 = 0.f, t2 = 0.f, t3 = 0.f, t4 = 0.f;
  const int qbase = wid * 512;           // f32x4 units: 512 per wave quarter
#pragma unroll
  for (int q = 0; q < 8; ++q) {
    f32x4 s4 = Bv[qbase + q * 64 + lane];
    VINS(s4.x) VINS(s4.y) VINS(s4.z) VINS(s4.w)
  }
  // ---- value-only butterfly merge of sorted-5 lists across 64 lanes
#pragma unroll
  for (int s = 32; s; s >>= 1) {
    float o0 = __shfl_xor(t0, s), o1 = __shfl_xor(t1, s), o2 = __shfl_xor(t2, s),
          o3 = __shfl_xor(t3, s), o4 = __shfl_xor(t4, s);
    VINS(o0) VINS(o1) VINS(o2) VINS(o3) VINS(o4)
  }
  if (lane == 0) { wt[wid][0]=t0; wt[wid][1]=t1; wt[wid][2]=t2; wt[wid][3]=t3; wt[wid][4]=t4; }
  __syncthreads();                       // B3: wave tops ready

  // ---- all threads redundantly merge the 4 wave lists (broadcast reads)
  t0 = wt[0][0]; t1 = wt[0][1]; t2 = wt[0][2]; t3 = wt[0][3]; t4 = wt[0][4];
#pragma unroll
  for (int w = 1; w < NT / 64; ++w) {
    VINS(wt[w][0]) VINS(wt[w][1]) VINS(wt[w][2]) VINS(wt[w][3]) VINS(wt[w][4])
  }
  const float m5 = t4, m1 = t0;
  const float au = a[u];

  // ---- compact survivors (raw val >= m5, positive); rare branch
#pragma unroll
  for (int q = 0; q < 8; ++q) {
    f32x4 s4 = Bv[qbase + q * 64 + lane];
    int col0 = (qbase + q * 64 + lane) * 4;
#pragma unroll
    for (int z = 0; z < 4; ++z) {
      float v = (z == 0) ? s4.x : (z == 1) ? s4.y : (z == 2) ? s4.z : s4.w;
      if (v >= m5 && v > 0.f) {
        int slot = atomicAdd(&scnt, 1);
        if (slot < KS) {
          val5[u * KS + slot] = au * v;
          idx5[u * KS + slot] = col0 + z;
        }
      }
    }
  }
  __syncthreads();                       // scnt final
  if (tid == 0) {
    nk[u] = scnt < KS ? scnt : KS;
    if (m1 > 0.f) atomicMax(gmax, __float_as_uint(au * m1)); // bits==float order
  }

  // ---- LAST: stream this row's zeros (no loads after this point; the
  // store queue drains under the next resident block's compute)
  f32x4* orow = reinterpret_cast<f32x4*>(out + (size_t)u * U);
#pragma unroll
  for (int q = 0; q < U / 4 / NT; ++q)
    __builtin_nontemporal_store(zz4, &orow[q * NT + tid]);
}

// ----------------------------------------------------------------- k_norm
// Splice the normalized kept values (~U*5 scattered 4B stores).
__global__ __launch_bounds__(NTB) void k_norm(
    const float* __restrict__ val5, const int* __restrict__ idx5,
    const int* __restrict__ nk, const unsigned* __restrict__ gmax,
    float* __restrict__ out) {
  int i = blockIdx.x * NTB + threadIdx.x;
  if (i >= U * KS) return;
  int u = i / KS, s = i - u * KS;
  if (s < nk[u]) {
    float inv = 1.f / (__uint_as_float(*gmax) + EPSF);
    out[(size_t)u * U + idx5[i]] = val5[i] * inv;
  }
}

// ------------------------------------------------------------------ host
extern "C" void kernel_launch(void* const* d_in, const int* in_sizes, int n_in,
                              void* d_out, int out_size, void* d_ws, size_t ws_size,
                              hipStream_t stream) {
  const int M = in_sizes[0] / 2;                    // 196608
  const int* uidx = (const int*)d_in[0];            // edge_index_ui row 0
  const int* iidx = uidx + M;                       // edge_index_ui row 1
  const float* fraud_u = (const float*)d_in[1];
  // d_in[2] fraud_i: unused (use_item_gamma=False)
  const float* theta = (const float*)d_in[3];
  const float* gamma = (const float*)d_in[4];

  int* ws = (int*)d_ws;
  int*      cnt   = ws;                             // [U]
  int*      degi  = ws + U;                         // [NI]
  unsigned* gmax  = (unsigned*)(ws + U + NI);       // [1] (+3 pad)
  float*    a     = (float*)(ws + U + NI + 4);      // [U]
  float*    t     = a + U;                          // [NI]
  float*    val5  = t + NI;                         // [U*KS]
  int*      idx5  = (int*)(val5 + U * KS);          // [U*KS]
  int*      nk    = idx5 + U * KS;                  // [U]
  int*      items = nk + U;                         // [U*MAXDU]
  float*    val_e = (float*)(items + U * MAXDU);    // [M]
  float* out = (float*)d_out;

  (void)hipMemsetAsync(d_ws, 0, (size_t)(U + NI + 4) * sizeof(int), stream);
  k_build  <<<(M + NTB - 1) / NTB, NTB, 0, stream>>>(uidx, iidx, M, cnt, degi, items);
  k_scalars<<<U / NTB,             NTB, 0, stream>>>(cnt, degi, fraud_u, theta, gamma, a, t);
  k_edges  <<<(M + NTB - 1) / NTB, NTB, 0, stream>>>(uidx, iidx, M, a, t, val_e);
  k_rows   <<<U,                   NT,  0, stream>>>(uidx, cnt, items, a, val_e,
                                                     val5, idx5, nk, gmax, out);
  k_norm   <<<(U * KS + NTB - 1) / NTB, NTB, 0, stream>>>(val5, idx5, nk, gmax, out);
}

// Round 13
// 192.997 us; speedup vs baseline: 2.1366x; 1.0019x over previous
//
#include <hip/hip_runtime.h>
#include <math.h>

// LearnableProjector: P[u,v] = a[u]*a[v]*sum_{j in common items} t[j];
// per-row top-5 keep (ties included, like reference P >= kth), global
// max-normalize. Output dense [8192][8192] f32.
//
// R13: R12 with PLAIN (write-back) stores for the zero-stream instead of
// nontemporal. R12's counters showed nt stores drain at ~1.75 TB/s and the
// backlog stalls the next replay's first dispatch ~150us; the runtime's
// plain-store fill kernel sustained 6.9 TB/s raw. Single-flag A/B.

#define EPSF 1e-8f
constexpr int U     = 8192;   // num_users
constexpr int NI    = 4096;   // num_items
constexpr int DEG   = 48;     // edges per item; edges grouped by item
constexpr int MAXDU = 48;     // deg_u <= 48
constexpr int NTB   = 256;    // prep kernels block size
constexpr int NT    = 256;    // k_rows block size
constexpr int KS    = 8;      // survivor slots per row (top-5 + tie slack)

typedef float f32x4 __attribute__((ext_vector_type(4)));

// branchless value-only insert into descending t0..t4 (10 full-rate ops)
#define VINS(xin) { float nx = (xin), mx;                                     \
  mx = fmaxf(t0, nx); nx = fminf(t0, nx); t0 = mx;                            \
  mx = fmaxf(t1, nx); nx = fminf(t1, nx); t1 = mx;                            \
  mx = fmaxf(t2, nx); nx = fminf(t2, nx); t2 = mx;                            \
  mx = fmaxf(t3, nx); nx = fminf(t3, nx); t3 = mx;                            \
  t4 = fmaxf(t4, nx); }

// ---------------------------------------------------------------- k_build
__global__ __launch_bounds__(NTB) void k_build(
    const int* __restrict__ uidx, const int* __restrict__ iidx, int M,
    int* __restrict__ cnt, int* __restrict__ degi, int* __restrict__ items) {
  int e = blockIdx.x * NTB + threadIdx.x;
  if (e >= M) return;
  int u = uidx[e];
  int j = iidx[e];
  atomicAdd(&degi[j], 1);
  int slot = atomicAdd(&cnt[u], 1);
  if (slot < MAXDU) items[u * MAXDU + slot] = j;
}

// -------------------------------------------------------------- k_scalars
__global__ __launch_bounds__(NTB) void k_scalars(
    const int* __restrict__ cnt, const int* __restrict__ degi,
    const float* __restrict__ fraud_u, const float* __restrict__ theta,
    const float* __restrict__ gamma, float* __restrict__ a, float* __restrict__ t) {
  int i = blockIdx.x * NTB + threadIdx.x;
  float g = gamma[0];
  if (i < U) {
    float su = log1pf((float)cnt[i]) * expf(g * fraud_u[i]);
    a[i] = sqrtf(su + EPSF);
  }
  if (i < NI) {
    float w  = log1pf(expf(theta[i])) + EPSF;   // softplus + EPS
    float si = log1pf((float)degi[i]);
    t[i] = (si + EPSF) * w;
  }
}

// ---------------------------------------------------------------- k_edges
// val_e[e] = t[i[e]] * a[u[e]]  (gathers done once, coalesced writes)
__global__ __launch_bounds__(NTB) void k_edges(
    const int* __restrict__ uidx, const int* __restrict__ iidx, int M,
    const float* __restrict__ a, const float* __restrict__ t,
    float* __restrict__ val_e) {
  int e = blockIdx.x * NTB + threadIdx.x;
  if (e >= M) return;
  val_e[e] = t[iidx[e]] * a[uidx[e]];
}

// ---------------------------------------------------------------- k_rows
// One row per block. Branchless value-only top-5 -> threshold -> compact,
// then stream the row's zeros with PLAIN stores (L2 write-back).
__global__ __launch_bounds__(NT) void k_rows(
    const int* __restrict__ uidx, const int* __restrict__ cnt,
    const int* __restrict__ items, const float* __restrict__ a,
    const float* __restrict__ val_e, float* __restrict__ val5,
    int* __restrict__ idx5, int* __restrict__ nk, unsigned* __restrict__ gmax,
    float* __restrict__ out) {
  __shared__ float row[U];               // 32 KB
  __shared__ int   shj[MAXDU];           // item list, pre-scaled *DEG
  __shared__ float wt[NT / 64][5];       // per-wave top-5 values
  __shared__ int   scnt;

  const int tid = threadIdx.x, lane = tid & 63, wid = tid >> 6;
  const int u = blockIdx.x;
  f32x4* Bv = reinterpret_cast<f32x4*>(row);
  const f32x4 zz4 = {0.f, 0.f, 0.f, 0.f};

  int c = cnt[u]; if (c > MAXDU) c = MAXDU;
  if (tid < c) shj[tid] = items[u * MAXDU + tid] * DEG;
  if (tid == 0) scnt = 0;
#pragma unroll
  for (int q = 0; q < U / 4 / NT; ++q) Bv[q * NT + tid] = zz4;
  __syncthreads();                       // B1: row zeroed, shj ready

  // ---- cooperative scatter: <= 9 edges per thread, LDS atomics
  const int total = c * DEG;
  for (int x = tid; x < total; x += NT) {
    int k = x / DEG;                     // compile-time 48 -> magic-mul
    int e = shj[k] + (x - k * DEG);
    int v = uidx[e];                     // coalesced within item span
    if (v != u) atomicAdd(&row[v], val_e[e]);
  }
  __syncthreads();                       // B2: all adds done

  // ---- per-lane branchless top-5 values over this wave's 2048-slot quarter
  float t0 = 0.f, t1 = 0.f, t2 = 0.f, t3 = 0.f, t4 = 0.f;
  const int qbase = wid * 512;           // f32x4 units: 512 per wave quarter
#pragma unroll
  for (int q = 0; q < 8; ++q) {
    f32x4 s4 = Bv[qbase + q * 64 + lane];
    VINS(s4.x) VINS(s4.y) VINS(s4.z) VINS(s4.w)
  }
  // ---- value-only butterfly merge of sorted-5 lists across 64 lanes
#pragma unroll
  for (int s = 32; s; s >>= 1) {
    float o0 = __shfl_xor(t0, s), o1 = __shfl_xor(t1, s), o2 = __shfl_xor(t2, s),
          o3 = __shfl_xor(t3, s), o4 = __shfl_xor(t4, s);
    VINS(o0) VINS(o1) VINS(o2) VINS(o3) VINS(o4)
  }
  if (lane == 0) { wt[wid][0]=t0; wt[wid][1]=t1; wt[wid][2]=t2; wt[wid][3]=t3; wt[wid][4]=t4; }
  __syncthreads();                       // B3: wave tops ready

  // ---- all threads redundantly merge the 4 wave lists (broadcast reads)
  t0 = wt[0][0]; t1 = wt[0][1]; t2 = wt[0][2]; t3 = wt[0][3]; t4 = wt[0][4];
#pragma unroll
  for (int w = 1; w < NT / 64; ++w) {
    VINS(wt[w][0]) VINS(wt[w][1]) VINS(wt[w][2]) VINS(wt[w][3]) VINS(wt[w][4])
  }
  const float m5 = t4, m1 = t0;
  const float au = a[u];

  // ---- compact survivors (raw val >= m5, positive); rare branch
#pragma unroll
  for (int q = 0; q < 8; ++q) {
    f32x4 s4 = Bv[qbase + q * 64 + lane];
    int col0 = (qbase + q * 64 + lane) * 4;
#pragma unroll
    for (int z = 0; z < 4; ++z) {
      float v = (z == 0) ? s4.x : (z == 1) ? s4.y : (z == 2) ? s4.z : s4.w;
      if (v >= m5 && v > 0.f) {
        int slot = atomicAdd(&scnt, 1);
        if (slot < KS) {
          val5[u * KS + slot] = au * v;
          idx5[u * KS + slot] = col0 + z;
        }
      }
    }
  }
  __syncthreads();                       // scnt final
  if (tid == 0) {
    nk[u] = scnt < KS ? scnt : KS;
    if (m1 > 0.f) atomicMax(gmax, __float_as_uint(au * m1)); // bits==float order
  }

  // ---- LAST: stream this row's zeros with PLAIN stores (L2 write-back;
  // dirty lines evict to HBM at streaming rate, no nt slow path)
  f32x4* orow = reinterpret_cast<f32x4*>(out + (size_t)u * U);
#pragma unroll
  for (int q = 0; q < U / 4 / NT; ++q)
    orow[q * NT + tid] = zz4;
}

// ----------------------------------------------------------------- k_norm
// Splice the normalized kept values (~U*5 scattered 4B stores).
__global__ __launch_bounds__(NTB) void k_norm(
    const float* __restrict__ val5, const int* __restrict__ idx5,
    const int* __restrict__ nk, const unsigned* __restrict__ gmax,
    float* __restrict__ out) {
  int i = blockIdx.x * NTB + threadIdx.x;
  if (i >= U * KS) return;
  int u = i / KS, s = i - u * KS;
  if (s < nk[u]) {
    float inv = 1.f / (__uint_as_float(*gmax) + EPSF);
    out[(size_t)u * U + idx5[i]] = val5[i] * inv;
  }
}

// ------------------------------------------------------------------ host
extern "C" void kernel_launch(void* const* d_in, const int* in_sizes, int n_in,
                              void* d_out, int out_size, void* d_ws, size_t ws_size,
                              hipStream_t stream) {
  const int M = in_sizes[0] / 2;                    // 196608
  const int* uidx = (const int*)d_in[0];            // edge_index_ui row 0
  const int* iidx = uidx + M;                       // edge_index_ui row 1
  const float* fraud_u = (const float*)d_in[1];
  // d_in[2] fraud_i: unused (use_item_gamma=False)
  const float* theta = (const float*)d_in[3];
  const float* gamma = (const float*)d_in[4];

  int* ws = (int*)d_ws;
  int*      cnt   = ws;                             // [U]
  int*      degi  = ws + U;                         // [NI]
  unsigned* gmax  = (unsigned*)(ws + U + NI);       // [1] (+3 pad)
  float*    a     = (float*)(ws + U + NI + 4);      // [U]
  float*    t     = a + U;                          // [NI]
  float*    val5  = t + NI;                         // [U*KS]
  int*      idx5  = (int*)(val5 + U * KS);          // [U*KS]
  int*      nk    = idx5 + U * KS;                  // [U]
  int*      items = nk + U;                         // [U*MAXDU]
  float*    val_e = (float*)(items + U * MAXDU);    // [M]
  float* out = (float*)d_out;

  (void)hipMemsetAsync(d_ws, 0, (size_t)(U + NI + 4) * sizeof(int), stream);
  k_build  <<<(M + NTB - 1) / NTB, NTB, 0, stream>>>(uidx, iidx, M, cnt, degi, items);
  k_scalars<<<U / NTB,             NTB, 0, stream>>>(cnt, degi, fraud_u, theta, gamma, a, t);
  k_edges  <<<(M + NTB - 1) / NTB, NTB, 0, stream>>>(uidx, iidx, M, a, t, val_e);
  k_rows   <<<U,                   NT,  0, stream>>>(uidx, cnt, items, a, val_e,
                                                     val5, idx5, nk, gmax, out);
  k_norm   <<<(U * KS + NTB - 1) / NTB, NTB, 0, stream>>>(val5, idx5, nk, gmax, out);
}